// Round 1
// baseline (767.762 us; speedup 1.0000x reference)
//
#include <hip/hip_runtime.h>
#include <hip/hip_bf16.h>
#include <stdint.h>

typedef __attribute__((ext_vector_type(8))) short short8;
typedef __attribute__((ext_vector_type(4))) float f32x4;

#define DEVINL static __device__ __forceinline__

// ---------- helpers ----------
DEVINL unsigned short f2bf(float x) {
  union { float f; unsigned int u; } c; c.f = x;
  unsigned int u = c.u;
  u += 0x7fffu + ((u >> 16) & 1u);   // RNE
  return (unsigned short)(u >> 16);
}

DEVINL f32x4 mfma16(short8 a, short8 b, f32x4 c) {
  return __builtin_amdgcn_mfma_f32_16x16x32_bf16(a, b, c, 0, 0, 0);
}

DEVINL void gload16(const void* g, void* l) {
  __builtin_amdgcn_global_load_lds((const __attribute__((address_space(1))) void*)g,
                                   (__attribute__((address_space(3))) void*)l, 16, 0, 0);
}

// ---------- problem constants ----------
static constexpr int BB = 2, SS = 2048, HH = 3072;
static constexpr int NH = 24, NKV = 8, HD = 128, NREP = 3;
static constexpr int MM = BB * SS;            // 4096 token rows
static constexpr int KQ = NH * HD;            // 3072
static constexpr int KKV = NKV * HD;          // 1024

// ---------- fp32 -> bf16 convert ----------
__global__ void k_cvt(const float* __restrict__ in, unsigned short* __restrict__ out, int n) {
  int i = (blockIdx.x * 256 + threadIdx.x) * 4;
  if (i >= n) return;
  float4 v = *reinterpret_cast<const float4*>(in + i);
  ushort4 o;
  o.x = f2bf(v.x); o.y = f2bf(v.y); o.z = f2bf(v.z); o.w = f2bf(v.w);
  *reinterpret_cast<ushort4*>(out + i) = o;
}

// ---------- weight transpose + convert: in fp32 [R][C] -> out bf16 [C][R] ----------
__global__ void k_tcvt(const float* __restrict__ in, unsigned short* __restrict__ out,
                       int R, int C) {
  __shared__ float t[32][33];
  int tx = threadIdx.x & 31, ty = threadIdx.x >> 5;   // 32 x 8
  int r0 = blockIdx.y * 32, c0 = blockIdx.x * 32;
#pragma unroll
  for (int i = 0; i < 32; i += 8)
    t[ty + i][tx] = in[(long)(r0 + ty + i) * C + c0 + tx];
  __syncthreads();
#pragma unroll
  for (int i = 0; i < 32; i += 8)
    out[(long)(c0 + ty + i) * R + r0 + tx] = f2bf(t[tx][ty + i]);
}

// ---------- V transpose (bf16): V[b][s][kv*128+d] -> VT[b][kv][d][s] ----------
__global__ void k_vt(const unsigned short* __restrict__ V, unsigned short* __restrict__ VT) {
  __shared__ unsigned short t[32][33];
  int b = blockIdx.z >> 3, kv = blockIdx.z & 7;
  int tx = threadIdx.x & 31, ty = threadIdx.x >> 5;
  int d0 = blockIdx.x * 32, s0 = blockIdx.y * 32;
  const unsigned short* src = V + ((long)b * SS) * KKV + kv * HD;
  unsigned short* dst = VT + (long)(b * NKV + kv) * HD * SS;
#pragma unroll
  for (int i = 0; i < 32; i += 8)
    t[ty + i][tx] = src[(long)(s0 + ty + i) * KKV + d0 + tx];
  __syncthreads();
#pragma unroll
  for (int i = 0; i < 32; i += 8)
    dst[(long)(d0 + ty + i) * SS + s0 + tx] = t[tx][ty + i];
}

// ---------- bf16 GEMM, m97-style: C[M][N] = A[M][K] * Bt[N][K]^T ----------
// 128x128 tile, BK=64, 4 waves (2x2, 64x64 each), global_load_lds w/ XOR swizzle.
template <typename OutT>
__global__ __launch_bounds__(256, 2) void k_gemm(const unsigned short* __restrict__ A,
                                                 const unsigned short* __restrict__ Bt,
                                                 OutT* __restrict__ C,
                                                 int M, int N, int K) {
  __shared__ alignas(16) unsigned short As[128 * 64];
  __shared__ alignas(16) unsigned short Bs[128 * 64];
  const int tid = threadIdx.x;
  const int wave = tid >> 6, lane = tid & 63;
  const int l15 = lane & 15, g = lane >> 4;
  const int wr = wave >> 1, wc = wave & 1;
  const long m0 = (long)blockIdx.y * 128, n0 = (long)blockIdx.x * 128;

  f32x4 acc[4][4] = {{{0.f,0.f,0.f,0.f}}};

  for (long k0 = 0; k0 < K; k0 += 64) {
#pragma unroll
    for (int j = 0; j < 4; ++j) {
      int idx = j * 256 + wave * 64 + lane;
      int row = idx >> 3, sub = idx & 7;
      int sc_ = (sub ^ (row & 7)) * 8;               // pre-swizzled global source
      gload16(A  + (m0 + row) * K + k0 + sc_, (char*)As + (j * 4 + wave) * 1024);
      gload16(Bt + (n0 + row) * K + k0 + sc_, (char*)Bs + (j * 4 + wave) * 1024);
    }
    __syncthreads();
#pragma unroll
    for (int ks = 0; ks < 2; ++ks) {
      short8 a[4], b[4];
#pragma unroll
      for (int m = 0; m < 4; ++m) {
        int row = wr * 64 + m * 16 + l15;
        int cb = (ks * 64 + g * 16) ^ ((row & 7) << 4);   // swizzled read
        a[m] = *reinterpret_cast<const short8*>((const char*)As + row * 128 + cb);
      }
#pragma unroll
      for (int n = 0; n < 4; ++n) {
        int row = wc * 64 + n * 16 + l15;
        int cb = (ks * 64 + g * 16) ^ ((row & 7) << 4);
        b[n] = *reinterpret_cast<const short8*>((const char*)Bs + row * 128 + cb);
      }
#pragma unroll
      for (int m = 0; m < 4; ++m)
#pragma unroll
        for (int n = 0; n < 4; ++n)
          acc[m][n] = mfma16(a[m], b[n], acc[m][n]);
    }
    __syncthreads();
  }

#pragma unroll
  for (int m = 0; m < 4; ++m)
#pragma unroll
    for (int n = 0; n < 4; ++n)
#pragma unroll
      for (int r = 0; r < 4; ++r) {
        long row = m0 + wr * 64 + m * 16 + g * 4 + r;
        long col = n0 + wc * 64 + n * 16 + l15;
        float v = acc[m][n][r];
        if constexpr (sizeof(OutT) == 2) C[row * N + col] = f2bf(v);
        else                             C[row * N + col] = v;
      }
}

// ---------- flash attention ----------
// grid: (S/128, NH, B); 4 waves, each owns 32 q rows. K/V read direct (L2-resident).
__global__ __launch_bounds__(256, 2) void k_attn(const unsigned short* __restrict__ Q,
                                                 const unsigned short* __restrict__ Kb,
                                                 const unsigned short* __restrict__ VT,
                                                 const float* __restrict__ mask,
                                                 unsigned short* __restrict__ AO) {
  const int b = blockIdx.z, h = blockIdx.y, kv = h / NREP;
  const int lane = threadIdx.x & 63, wave = threadIdx.x >> 6;
  const int l15 = lane & 15, g = lane >> 4;
  const int qbase = blockIdx.x * 128 + wave * 32;

  const unsigned short* Qp = Q + ((long)b * SS + qbase) * KQ + h * HD;
  const unsigned short* Kp = Kb + (long)b * SS * KKV + kv * HD;
  const unsigned short* Vp = VT + (long)(b * NKV + kv) * HD * SS;
  const float* Mp = mask + (long)b * SS * SS + (long)qbase * SS;

  // wave-private P tile [32 rows][64 cols], padded stride 88 (176 B, 16B-aligned)
  __shared__ alignas(16) unsigned short Pl[4][32 * 88];
  unsigned short* Pw = Pl[wave];

  const float LOG2E = 1.4426950408889634f;
  const float SC2 = 0.08838834764831845f * LOG2E;   // 1/sqrt(128) * log2(e)

  short8 qf[2][4];
#pragma unroll
  for (int m = 0; m < 2; ++m)
#pragma unroll
    for (int d = 0; d < 4; ++d)
      qf[m][d] = *reinterpret_cast<const short8*>(Qp + (long)(m * 16 + l15) * KQ + d * 32 + g * 8);

  f32x4 o[2][8] = {{{0.f,0.f,0.f,0.f}}};
  float mrun[2][4], lrun[2][4];
#pragma unroll
  for (int m = 0; m < 2; ++m)
#pragma unroll
    for (int r = 0; r < 4; ++r) { mrun[m][r] = -1e30f; lrun[m][r] = 0.f; }

  for (int kt = 0; kt < SS; kt += 64) {
    // ---- QK^T: sc[m][blk] over 64 keys ----
    f32x4 sc[2][4] = {{{0.f,0.f,0.f,0.f}}};
#pragma unroll
    for (int blk = 0; blk < 4; ++blk) {
      short8 kf[4];
#pragma unroll
      for (int d = 0; d < 4; ++d)
        kf[d] = *reinterpret_cast<const short8*>(
            Kp + (long)(kt + blk * 16 + l15) * KKV + d * 32 + g * 8);
#pragma unroll
      for (int d = 0; d < 4; ++d) {
        sc[0][blk] = mfma16(qf[0][d], kf[d], sc[0][blk]);
        sc[1][blk] = mfma16(qf[1][d], kf[d], sc[1][blk]);
      }
    }
    // ---- mask + online softmax (exp2 domain) ----
#pragma unroll
    for (int m = 0; m < 2; ++m) {
#pragma unroll
      for (int r = 0; r < 4; ++r) {
        const int qrow = m * 16 + g * 4 + r;
        const float* mrow = Mp + (long)qrow * SS + kt;
        float tm = -1e30f;
#pragma unroll
        for (int blk = 0; blk < 4; ++blk) {
          float x = sc[m][blk][r] * SC2 + mrow[blk * 16 + l15] * LOG2E;
          sc[m][blk][r] = x;
          tm = fmaxf(tm, x);
        }
        tm = fmaxf(tm, __shfl_xor(tm, 1));
        tm = fmaxf(tm, __shfl_xor(tm, 2));
        tm = fmaxf(tm, __shfl_xor(tm, 4));
        tm = fmaxf(tm, __shfl_xor(tm, 8));
        float mn = fmaxf(mrun[m][r], tm);
        float corr = __builtin_amdgcn_exp2f(mrun[m][r] - mn);
        mrun[m][r] = mn;
        float ts = 0.f;
#pragma unroll
        for (int blk = 0; blk < 4; ++blk) {
          float pv = __builtin_amdgcn_exp2f(sc[m][blk][r] - mn);
          sc[m][blk][r] = pv;
          ts += pv;
        }
        ts += __shfl_xor(ts, 1); ts += __shfl_xor(ts, 2);
        ts += __shfl_xor(ts, 4); ts += __shfl_xor(ts, 8);
        lrun[m][r] = lrun[m][r] * corr + ts;
#pragma unroll
        for (int db = 0; db < 8; ++db) o[m][db][r] *= corr;
#pragma unroll
        for (int blk = 0; blk < 4; ++blk)
          Pw[qrow * 88 + blk * 16 + l15] = f2bf(sc[m][blk][r]);
      }
    }
    asm volatile("s_waitcnt lgkmcnt(0)" ::: "memory");   // drain P writes (wave-private LDS)
    // ---- PV ----
#pragma unroll
    for (int ks = 0; ks < 2; ++ks) {
      short8 pa0 = *reinterpret_cast<const short8*>((const char*)Pw + l15 * 176 + ks * 64 + g * 16);
      short8 pa1 = *reinterpret_cast<const short8*>((const char*)Pw + (16 + l15) * 176 + ks * 64 + g * 16);
#pragma unroll
      for (int db = 0; db < 8; ++db) {
        short8 vf = *reinterpret_cast<const short8*>(
            Vp + (long)(db * 16 + l15) * SS + kt + ks * 32 + g * 8);
        o[0][db] = mfma16(pa0, vf, o[0][db]);
        o[1][db] = mfma16(pa1, vf, o[1][db]);
      }
    }
  }

  // ---- epilogue: divide by l, store bf16 ----
#pragma unroll
  for (int m = 0; m < 2; ++m) {
    float inv[4];
#pragma unroll
    for (int r = 0; r < 4; ++r) inv[r] = 1.f / lrun[m][r];
#pragma unroll
    for (int db = 0; db < 8; ++db)
#pragma unroll
      for (int r = 0; r < 4; ++r) {
        long row = qbase + m * 16 + g * 4 + r;
        AO[((long)b * SS + row) * KQ + h * HD + db * 16 + l15] = f2bf(o[m][db][r] * inv[r]);
      }
  }
}

// ---------- launch ----------
extern "C" void kernel_launch(void* const* d_in, const int* in_sizes, int n_in,
                              void* d_out, int out_size, void* d_ws, size_t ws_size,
                              hipStream_t stream) {
  const float* hidden = (const float*)d_in[0];
  const float* mask   = (const float*)d_in[1];
  const float* Wq     = (const float*)d_in[2];
  const float* Wk     = (const float*)d_in[3];
  const float* Wv     = (const float*)d_in[4];
  const float* Wo     = (const float*)d_in[5];

  char* ws = (char*)d_ws;
  constexpr long SZ_X   = (long)MM * HH * 2;          // 25.2 MB bf16
  constexpr long SZ_WQT = (long)HH * KQ * 2;          // 18.9 MB
  constexpr long SZ_WKT = (long)HH * KKV * 2;         // 6.3 MB
  constexpr long SZ_QKV = (long)MM * KKV * 2;         // 8.4 MB
  unsigned short* Xb  = (unsigned short*)(ws);
  unsigned short* WqT = (unsigned short*)(ws + SZ_X);
  unsigned short* WkT = (unsigned short*)(ws + SZ_X + SZ_WQT);
  unsigned short* WvT = (unsigned short*)(ws + SZ_X + SZ_WQT + SZ_WKT);
  unsigned short* WoT = (unsigned short*)(ws + SZ_X + SZ_WQT + 2 * SZ_WKT);
  unsigned short* Qb  = (unsigned short*)(ws + SZ_X + 2 * SZ_WQT + 2 * SZ_WKT);
  unsigned short* Kb  = (unsigned short*)(ws + 2 * SZ_X + 2 * SZ_WQT + 2 * SZ_WKT);
  unsigned short* Vb  = (unsigned short*)(ws + 2 * SZ_X + 2 * SZ_WQT + 2 * SZ_WKT + SZ_QKV);
  unsigned short* VTb = (unsigned short*)(ws + 2 * SZ_X + 2 * SZ_WQT + 2 * SZ_WKT + 2 * SZ_QKV);
  unsigned short* AOb = (unsigned short*)(ws + 2 * SZ_X + 2 * SZ_WQT + 2 * SZ_WKT + 3 * SZ_QKV);

  // 1) converts / weight transposes
  k_cvt<<<(MM * HH) / 1024, 256, 0, stream>>>(hidden, Xb, MM * HH);
  k_tcvt<<<dim3(KQ / 32, HH / 32), 256, 0, stream>>>(Wq, WqT, HH, KQ);
  k_tcvt<<<dim3(KKV / 32, HH / 32), 256, 0, stream>>>(Wk, WkT, HH, KKV);
  k_tcvt<<<dim3(KKV / 32, HH / 32), 256, 0, stream>>>(Wv, WvT, HH, KKV);
  k_tcvt<<<dim3(KQ / 32, HH / 32), 256, 0, stream>>>(Wo, WoT, KQ, HH);

  // 2) projections
  k_gemm<unsigned short><<<dim3(KQ / 128, MM / 128), 256, 0, stream>>>(Xb, WqT, Qb, MM, KQ, HH);
  k_gemm<unsigned short><<<dim3(KKV / 128, MM / 128), 256, 0, stream>>>(Xb, WkT, Kb, MM, KKV, HH);
  k_gemm<unsigned short><<<dim3(KKV / 128, MM / 128), 256, 0, stream>>>(Xb, WvT, Vb, MM, KKV, HH);

  // 3) V -> V^T
  k_vt<<<dim3(HD / 32, SS / 32, BB * NKV), 256, 0, stream>>>(Vb, VTb);

  // 4) attention
  k_attn<<<dim3(SS / 128, NH, BB), 256, 0, stream>>>(Qb, Kb, VTb, mask, AOb);

  // 5) output projection -> fp32 d_out
  k_gemm<float><<<dim3(HH / 128, MM / 128), 256, 0, stream>>>(AOb, WoT, (float*)d_out, MM, HH, HH);
}

// Round 2
// 746.250 us; speedup vs baseline: 1.0288x; 1.0288x over previous
//
#include <hip/hip_runtime.h>
#include <hip/hip_bf16.h>
#include <stdint.h>

typedef __attribute__((ext_vector_type(8))) short short8;
typedef __attribute__((ext_vector_type(4))) float f32x4;

#define DEVINL static __device__ __forceinline__

// ---------- helpers ----------
DEVINL unsigned short f2bf(float x) {
  union { float f; unsigned int u; } c; c.f = x;
  unsigned int u = c.u;
  u += 0x7fffu + ((u >> 16) & 1u);   // RNE
  return (unsigned short)(u >> 16);
}

DEVINL f32x4 mfma16(short8 a, short8 b, f32x4 c) {
  return __builtin_amdgcn_mfma_f32_16x16x32_bf16(a, b, c, 0, 0, 0);
}

DEVINL void gload16(const void* g, void* l) {
  __builtin_amdgcn_global_load_lds((const __attribute__((address_space(1))) void*)g,
                                   (__attribute__((address_space(3))) void*)l, 16, 0, 0);
}

// ---------- problem constants ----------
static constexpr int BB = 2, SS = 2048, HH = 3072;
static constexpr int NH = 24, NKV = 8, HD = 128, NREP = 3;
static constexpr int MM = BB * SS;            // 4096 token rows
static constexpr int KQ = NH * HD;            // 3072
static constexpr int KKV = NKV * HD;          // 1024

// ---------- fp32 -> bf16 convert ----------
__global__ void k_cvt(const float* __restrict__ in, unsigned short* __restrict__ out, int n) {
  int i = (blockIdx.x * 256 + threadIdx.x) * 4;
  if (i >= n) return;
  float4 v = *reinterpret_cast<const float4*>(in + i);
  ushort4 o;
  o.x = f2bf(v.x); o.y = f2bf(v.y); o.z = f2bf(v.z); o.w = f2bf(v.w);
  *reinterpret_cast<ushort4*>(out + i) = o;
}

// ---------- weight transpose + convert: in fp32 [R][C] -> out bf16 [C][R] ----------
__global__ void k_tcvt(const float* __restrict__ in, unsigned short* __restrict__ out,
                       int R, int C) {
  __shared__ float t[32][33];
  int tx = threadIdx.x & 31, ty = threadIdx.x >> 5;   // 32 x 8
  int r0 = blockIdx.y * 32, c0 = blockIdx.x * 32;
#pragma unroll
  for (int i = 0; i < 32; i += 8)
    t[ty + i][tx] = in[(long)(r0 + ty + i) * C + c0 + tx];
  __syncthreads();
#pragma unroll
  for (int i = 0; i < 32; i += 8)
    out[(long)(c0 + ty + i) * R + r0 + tx] = f2bf(t[tx][ty + i]);
}

// ---------- V transpose (bf16): V[b][s][kv*128+d] -> VT[b][kv][d][s] ----------
__global__ void k_vt(const unsigned short* __restrict__ V, unsigned short* __restrict__ VT) {
  __shared__ unsigned short t[32][33];
  int b = blockIdx.z >> 3, kv = blockIdx.z & 7;
  int tx = threadIdx.x & 31, ty = threadIdx.x >> 5;
  int d0 = blockIdx.x * 32, s0 = blockIdx.y * 32;
  const unsigned short* src = V + ((long)b * SS) * KKV + kv * HD;
  unsigned short* dst = VT + (long)(b * NKV + kv) * HD * SS;
#pragma unroll
  for (int i = 0; i < 32; i += 8)
    t[ty + i][tx] = src[(long)(s0 + ty + i) * KKV + d0 + tx];
  __syncthreads();
#pragma unroll
  for (int i = 0; i < 32; i += 8)
    dst[(long)(d0 + ty + i) * SS + s0 + tx] = t[tx][ty + i];
}

// ---------- bf16 GEMM, m97-style: C[M][N] = A[M][K] * Bt[N][K]^T ----------
template <typename OutT>
__global__ __launch_bounds__(256, 2) void k_gemm(const unsigned short* __restrict__ A,
                                                 const unsigned short* __restrict__ Bt,
                                                 OutT* __restrict__ C,
                                                 int M, int N, int K) {
  __shared__ alignas(16) unsigned short As[128 * 64];
  __shared__ alignas(16) unsigned short Bs[128 * 64];
  const int tid = threadIdx.x;
  const int wave = tid >> 6, lane = tid & 63;
  const int l15 = lane & 15, g = lane >> 4;
  const int wr = wave >> 1, wc = wave & 1;
  const long m0 = (long)blockIdx.y * 128, n0 = (long)blockIdx.x * 128;

  f32x4 acc[4][4] = {{{0.f,0.f,0.f,0.f}}};

  for (long k0 = 0; k0 < K; k0 += 64) {
#pragma unroll
    for (int j = 0; j < 4; ++j) {
      int idx = j * 256 + wave * 64 + lane;
      int row = idx >> 3, sub = idx & 7;
      int sc_ = (sub ^ (row & 7)) * 8;               // pre-swizzled global source
      gload16(A  + (m0 + row) * K + k0 + sc_, (char*)As + (j * 4 + wave) * 1024);
      gload16(Bt + (n0 + row) * K + k0 + sc_, (char*)Bs + (j * 4 + wave) * 1024);
    }
    __syncthreads();
#pragma unroll
    for (int ks = 0; ks < 2; ++ks) {
      short8 a[4], b[4];
#pragma unroll
      for (int m = 0; m < 4; ++m) {
        int row = wr * 64 + m * 16 + l15;
        int cb = (ks * 64 + g * 16) ^ ((row & 7) << 4);   // swizzled read
        a[m] = *reinterpret_cast<const short8*>((const char*)As + row * 128 + cb);
      }
#pragma unroll
      for (int n = 0; n < 4; ++n) {
        int row = wc * 64 + n * 16 + l15;
        int cb = (ks * 64 + g * 16) ^ ((row & 7) << 4);
        b[n] = *reinterpret_cast<const short8*>((const char*)Bs + row * 128 + cb);
      }
#pragma unroll
      for (int m = 0; m < 4; ++m)
#pragma unroll
        for (int n = 0; n < 4; ++n)
          acc[m][n] = mfma16(a[m], b[n], acc[m][n]);
    }
    __syncthreads();
  }

#pragma unroll
  for (int m = 0; m < 4; ++m)
#pragma unroll
    for (int n = 0; n < 4; ++n)
#pragma unroll
      for (int r = 0; r < 4; ++r) {
        long row = m0 + wr * 64 + m * 16 + g * 4 + r;
        long col = n0 + wc * 64 + n * 16 + l15;
        float v = acc[m][n][r];
        if constexpr (sizeof(OutT) == 2) C[row * N + col] = f2bf(v);
        else                             C[row * N + col] = v;
      }
}

// ---------- flash attention, swapped-QK^T, LDS-staged K, double-buffered ----------
// grid: 768 blocks (flattened, XCD-chunk swizzled); 4 waves x 32 q-rows = 128 q/block.
__global__ __launch_bounds__(256, 2) void k_attn(const unsigned short* __restrict__ Q,
                                                 const unsigned short* __restrict__ Kb,
                                                 const unsigned short* __restrict__ VT,
                                                 const float* __restrict__ mask,
                                                 unsigned short* __restrict__ AO) {
  const int tid = threadIdx.x;
  const int wave = tid >> 6, lane = tid & 63;
  const int l15 = lane & 15, g = lane >> 4;

  // XCD-chunk swizzle: 768 % 8 == 0, chunk = 96
  const int bid = blockIdx.x;
  const int swz = (bid & 7) * 96 + (bid >> 3);
  const int qt = swz & 15;
  const int h  = (swz >> 4) % NH;
  const int b  = swz / (16 * NH);
  const int kv = h / NREP;
  const int qbase = qt * 128 + wave * 32;

  const unsigned short* Qp = Q + ((long)b * SS + qbase) * KQ + h * HD;
  const unsigned short* Kg = Kb + (long)b * SS * KKV + kv * HD;
  const unsigned short* Vp = VT + (long)(b * NKV + kv) * HD * SS;
  const float* Mp = mask + (long)b * SS * SS + (long)qbase * SS;

  __shared__ alignas(16) unsigned short Ks[2][64 * 128];   // 2 x 16 KB, swizzled
  __shared__ alignas(16) unsigned short Pl[4][32 * 68];    // per-wave P, stride 136 B
  unsigned short* Pw = Pl[wave];

  const float LOG2E = 1.4426950408889634f;
  const float SC2 = 0.08838834764831845f * LOG2E;   // 1/sqrt(128) * log2(e)

  // Q fragments (b-operand): lane (g,l15) holds Q[qh*16+l15][c*32+g*8 ..]
  short8 qf[2][4];
#pragma unroll
  for (int qh = 0; qh < 2; ++qh)
#pragma unroll
    for (int c = 0; c < 4; ++c)
      qf[qh][c] = *reinterpret_cast<const short8*>(Qp + (long)(qh * 16 + l15) * KQ + c * 32 + g * 8);

  f32x4 o[2][8] = {{{0.f,0.f,0.f,0.f}}};
  float mrun[2] = {-1e30f, -1e30f}, lrun[2] = {0.f, 0.f};

  // K tile staging: [64 rows][16 subs of 16B], swizzled sub = (s&8)|((s^row)&7)
  auto stage = [&](int buf, int kt) {
#pragma unroll
    for (int j = 0; j < 4; ++j) {
      int idx = j * 256 + wave * 64 + lane;
      int row = idx >> 4, sub = idx & 15;
      int ssub = (sub & 8) | ((sub ^ row) & 7);
      gload16(Kg + (long)(kt + row) * KKV + ssub * 8,
              (char*)Ks[buf] + (j * 256 + wave * 64) * 16);
    }
  };

  stage(0, 0);
  __syncthreads();

  for (int t = 0; t < SS / 64; ++t) {
    const int kt = t * 64;
    if (t < SS / 64 - 1) stage((t + 1) & 1, kt + 64);
    const char* Kt = (const char*)Ks[t & 1];

    // ---- QK^T (swapped): sc[qh][blk] row=key g*4+r, col=q l15 ----
    f32x4 sc[2][4] = {{{0.f,0.f,0.f,0.f}}};
    __builtin_amdgcn_s_setprio(1);
#pragma unroll
    for (int blk = 0; blk < 4; ++blk) {
      short8 kf[4];
      const int row = blk * 16 + l15;
#pragma unroll
      for (int c = 0; c < 4; ++c) {
        int s = c * 4 + g;
        int ssub = (s & 8) | ((s ^ row) & 7);
        kf[c] = *reinterpret_cast<const short8*>(Kt + row * 256 + ssub * 16);
      }
#pragma unroll
      for (int c = 0; c < 4; ++c) {
        sc[0][blk] = mfma16(kf[c], qf[0][c], sc[0][blk]);
        sc[1][blk] = mfma16(kf[c], qf[1][c], sc[1][blk]);
      }
    }
    __builtin_amdgcn_s_setprio(0);

    // ---- scale + mask (float4) + tile max ----
    float tmax[2];
#pragma unroll
    for (int qh = 0; qh < 2; ++qh) {
      const float* mrow = Mp + (long)(qh * 16 + l15) * SS + kt;
      float mx = -1e30f;
#pragma unroll
      for (int blk = 0; blk < 4; ++blk) {
        float4 mk = *reinterpret_cast<const float4*>(mrow + blk * 16 + g * 4);
#pragma unroll
        for (int r = 0; r < 4; ++r) {
          float x = sc[qh][blk][r] * SC2 + (&mk.x)[r] * LOG2E;
          sc[qh][blk][r] = x;
          mx = fmaxf(mx, x);
        }
      }
      mx = fmaxf(mx, __shfl_xor(mx, 16));
      mx = fmaxf(mx, __shfl_xor(mx, 32));
      tmax[qh] = mx;
    }

    // ---- defer-max: rescale only when needed (wave-uniform) ----
    if (!__all((tmax[0] <= mrun[0] + 8.f) && (tmax[1] <= mrun[1] + 8.f))) {
#pragma unroll
      for (int qh = 0; qh < 2; ++qh) {
        float mn = fmaxf(mrun[qh], tmax[qh]);
        float corr = __builtin_amdgcn_exp2f(mrun[qh] - mn);
        mrun[qh] = mn;
        lrun[qh] *= corr;
#pragma unroll
        for (int r = 0; r < 4; ++r) {
          float cr = __shfl(corr, g * 4 + r);
#pragma unroll
          for (int db = 0; db < 8; ++db) o[qh][db][r] *= cr;
        }
      }
    }

    // ---- exp2, row-sum, pack P -> LDS (b64 per fragment) ----
#pragma unroll
    for (int qh = 0; qh < 2; ++qh) {
      float ts = 0.f;
#pragma unroll
      for (int blk = 0; blk < 4; ++blk) {
#pragma unroll
        for (int r = 0; r < 4; ++r) {
          float p = __builtin_amdgcn_exp2f(sc[qh][blk][r] - mrun[qh]);
          sc[qh][blk][r] = p;
          ts += p;
        }
        uint2 pk;
        pk.x = (unsigned int)f2bf(sc[qh][blk][0]) | ((unsigned int)f2bf(sc[qh][blk][1]) << 16);
        pk.y = (unsigned int)f2bf(sc[qh][blk][2]) | ((unsigned int)f2bf(sc[qh][blk][3]) << 16);
        *reinterpret_cast<uint2*>((char*)Pw + (qh * 16 + l15) * 136 + blk * 32 + g * 8) = pk;
      }
      ts += __shfl_xor(ts, 16);
      ts += __shfl_xor(ts, 32);
      lrun[qh] += ts;
    }

    // ---- PV: a=P rows(q), b=V^T rows(d) ----
    __builtin_amdgcn_s_setprio(1);
#pragma unroll
    for (int ks = 0; ks < 2; ++ks) {
      short8 pa0 = *reinterpret_cast<const short8*>((const char*)Pw + l15 * 136 + ks * 64 + g * 16);
      short8 pa1 = *reinterpret_cast<const short8*>((const char*)Pw + (16 + l15) * 136 + ks * 64 + g * 16);
#pragma unroll
      for (int db = 0; db < 8; ++db) {
        short8 vf = *reinterpret_cast<const short8*>(
            Vp + (long)(db * 16 + l15) * SS + kt + ks * 32 + g * 8);
        o[0][db] = mfma16(pa0, vf, o[0][db]);
        o[1][db] = mfma16(pa1, vf, o[1][db]);
      }
    }
    __builtin_amdgcn_s_setprio(0);

    __syncthreads();   // drains staging loads; next iter reads the other buffer
  }

  // ---- epilogue ----
#pragma unroll
  for (int qh = 0; qh < 2; ++qh) {
#pragma unroll
    for (int r = 0; r < 4; ++r) {
      float lq = __shfl(lrun[qh], g * 4 + r);
      float inv = 1.f / lq;
      long row = qbase + qh * 16 + g * 4 + r;
#pragma unroll
      for (int db = 0; db < 8; ++db)
        AO[((long)b * SS + row) * KQ + h * HD + db * 16 + l15] = f2bf(o[qh][db][r] * inv);
    }
  }
}

// ---------- launch ----------
extern "C" void kernel_launch(void* const* d_in, const int* in_sizes, int n_in,
                              void* d_out, int out_size, void* d_ws, size_t ws_size,
                              hipStream_t stream) {
  const float* hidden = (const float*)d_in[0];
  const float* mask   = (const float*)d_in[1];
  const float* Wq     = (const float*)d_in[2];
  const float* Wk     = (const float*)d_in[3];
  const float* Wv     = (const float*)d_in[4];
  const float* Wo     = (const float*)d_in[5];

  char* ws = (char*)d_ws;
  constexpr long SZ_X   = (long)MM * HH * 2;          // 25.2 MB bf16
  constexpr long SZ_WQT = (long)HH * KQ * 2;          // 18.9 MB
  constexpr long SZ_WKT = (long)HH * KKV * 2;         // 6.3 MB
  constexpr long SZ_QKV = (long)MM * KKV * 2;         // 8.4 MB
  unsigned short* Xb  = (unsigned short*)(ws);
  unsigned short* WqT = (unsigned short*)(ws + SZ_X);
  unsigned short* WkT = (unsigned short*)(ws + SZ_X + SZ_WQT);
  unsigned short* WvT = (unsigned short*)(ws + SZ_X + SZ_WQT + SZ_WKT);
  unsigned short* WoT = (unsigned short*)(ws + SZ_X + SZ_WQT + 2 * SZ_WKT);
  unsigned short* Qb  = (unsigned short*)(ws + SZ_X + 2 * SZ_WQT + 2 * SZ_WKT);
  unsigned short* Kb  = (unsigned short*)(ws + 2 * SZ_X + 2 * SZ_WQT + 2 * SZ_WKT);
  unsigned short* Vb  = (unsigned short*)(ws + 2 * SZ_X + 2 * SZ_WQT + 2 * SZ_WKT + SZ_QKV);
  unsigned short* VTb = (unsigned short*)(ws + 2 * SZ_X + 2 * SZ_WQT + 2 * SZ_WKT + 2 * SZ_QKV);
  unsigned short* AOb = (unsigned short*)(ws + 2 * SZ_X + 2 * SZ_WQT + 2 * SZ_WKT + 3 * SZ_QKV);

  // 1) converts / weight transposes
  k_cvt<<<(MM * HH) / 1024, 256, 0, stream>>>(hidden, Xb, MM * HH);
  k_tcvt<<<dim3(KQ / 32, HH / 32), 256, 0, stream>>>(Wq, WqT, HH, KQ);
  k_tcvt<<<dim3(KKV / 32, HH / 32), 256, 0, stream>>>(Wk, WkT, HH, KKV);
  k_tcvt<<<dim3(KKV / 32, HH / 32), 256, 0, stream>>>(Wv, WvT, HH, KKV);
  k_tcvt<<<dim3(KQ / 32, HH / 32), 256, 0, stream>>>(Wo, WoT, KQ, HH);

  // 2) projections
  k_gemm<unsigned short><<<dim3(KQ / 128, MM / 128), 256, 0, stream>>>(Xb, WqT, Qb, MM, KQ, HH);
  k_gemm<unsigned short><<<dim3(KKV / 128, MM / 128), 256, 0, stream>>>(Xb, WkT, Kb, MM, KKV, HH);
  k_gemm<unsigned short><<<dim3(KKV / 128, MM / 128), 256, 0, stream>>>(Xb, WvT, Vb, MM, KKV, HH);

  // 3) V -> V^T
  k_vt<<<dim3(HD / 32, SS / 32, BB * NKV), 256, 0, stream>>>(Vb, VTb);

  // 4) attention (flattened grid, XCD-swizzled)
  k_attn<<<16 * NH * BB, 256, 0, stream>>>(Qb, Kb, VTb, mask, AOb);

  // 5) output projection -> fp32 d_out
  k_gemm<float><<<dim3(HH / 128, MM / 128), 256, 0, stream>>>(AOb, WoT, (float*)d_out, MM, HH, HH);
}